// Round 14
// baseline (610.143 us; speedup 1.0000x reference)
//
#include <hip/hip_runtime.h>

typedef unsigned int uint;
typedef unsigned char uchar;

#define NB_MAX 256      // max buckets
#define NPB_MAX 2048    // max nodes per bucket

#if defined(__has_builtin)
#if __has_builtin(__builtin_amdgcn_cvt_pk_f32_fp8) && __has_builtin(__builtin_amdgcn_cvt_pk_fp8_f32)
#define HW_FP8 1
#endif
#endif

typedef __attribute__((ext_vector_type(2))) float v2f;

// ---------------- fp8 e4m3 codecs (internal z/h storage) ----------------
static __device__ __forceinline__ uint f2fp8_sw(float v) {
    v = fminf(fmaxf(v, -448.f), 448.f);
    uint u = __float_as_uint(v);
    uint s = (u >> 24) & 0x80u;
    uint mag = u & 0x7FFFFFFFu;
    uint r = mag + 0x7FFFFu + ((mag >> 20) & 1u);     // RNE to 3 mantissa bits
    if (r < 0x3C800000u) return s;                    // below 2^-6 -> ±0
    uint e8 = (r - 0x3C000000u) >> 20;
    return s | min(e8, 0x7Eu);
}
static __device__ __forceinline__ float fp82f(uint b) {
    uint mag = b & 0x7Fu;
    uint bits = ((b & 0x80u) << 24) | ((mag << 20) + 0x3C000000u);
    return mag ? __uint_as_float(bits) : 0.f;
}
static __device__ __forceinline__ void dec8(uint2 v, float* o) {
#ifdef HW_FP8
    v2f a = __builtin_amdgcn_cvt_pk_f32_fp8((int)v.x, false);
    v2f b = __builtin_amdgcn_cvt_pk_f32_fp8((int)v.x, true);
    v2f c = __builtin_amdgcn_cvt_pk_f32_fp8((int)v.y, false);
    v2f d = __builtin_amdgcn_cvt_pk_f32_fp8((int)v.y, true);
    o[0]=a.x; o[1]=a.y; o[2]=b.x; o[3]=b.y;
    o[4]=c.x; o[5]=c.y; o[6]=d.x; o[7]=d.y;
#else
    o[0]=fp82f(v.x&0xFF); o[1]=fp82f((v.x>>8)&0xFF); o[2]=fp82f((v.x>>16)&0xFF); o[3]=fp82f(v.x>>24);
    o[4]=fp82f(v.y&0xFF); o[5]=fp82f((v.y>>8)&0xFF); o[6]=fp82f((v.y>>16)&0xFF); o[7]=fp82f(v.y>>24);
#endif
}
static __device__ __forceinline__ uint2 enc8(const float* o) {
#ifdef HW_FP8
    int rx = __builtin_amdgcn_cvt_pk_fp8_f32(o[0], o[1], 0, false);
    rx = __builtin_amdgcn_cvt_pk_fp8_f32(o[2], o[3], rx, true);
    int ry = __builtin_amdgcn_cvt_pk_fp8_f32(o[4], o[5], 0, false);
    ry = __builtin_amdgcn_cvt_pk_fp8_f32(o[6], o[7], ry, true);
    return make_uint2((uint)rx, (uint)ry);
#else
    uint2 r;
    r.x = f2fp8_sw(o[0]) | (f2fp8_sw(o[1])<<8) | (f2fp8_sw(o[2])<<16) | (f2fp8_sw(o[3])<<24);
    r.y = f2fp8_sw(o[4]) | (f2fp8_sw(o[5])<<8) | (f2fp8_sw(o[6])<<16) | (f2fp8_sw(o[7])<<24);
    return r;
#endif
}
static __device__ __forceinline__ void dec32(const uchar* row, float* o) {
    const uint4* r4 = (const uint4*)row;
    uint4 A = r4[0], B = r4[1];
    dec8(make_uint2(A.x,A.y), o); dec8(make_uint2(A.z,A.w), o+8);
    dec8(make_uint2(B.x,B.y), o+16); dec8(make_uint2(B.z,B.w), o+24);
}
static __device__ __forceinline__ void enc32(const float* o, uchar* row) {
    uint2 a = enc8(o), b = enc8(o+8), c = enc8(o+16), d = enc8(o+24);
    uint4* r4 = (uint4*)row;
    r4[0] = make_uint4(a.x,a.y,b.x,b.y);
    r4[1] = make_uint4(c.x,c.y,d.x,d.y);
}

// ---------------- wave-level inclusive scan (64 lanes) ----------------
static __device__ __forceinline__ unsigned wave_incl_scan(unsigned v) {
    int lane = threadIdx.x & 63;
    #pragma unroll
    for (int d = 1; d < 64; d <<= 1) {
        unsigned t = (unsigned)__shfl_up((int)v, d, 64);
        if (lane >= d) v += t;
    }
    return v;
}

// exclusive block scan: in[0..n) -> out[0..n), n <= 2048, 256 threads, wscr = shared[4]
static __device__ void block_excl_scan(const uint* in, uint* out, int n, uint* wscr) {
    int tid = threadIdx.x;
    int lane = tid & 63, wid = tid >> 6;
    int base = tid * 8;
    uint v[8], pre[8], s = 0;
    #pragma unroll
    for (int k = 0; k < 8; k++) v[k] = (base + k < n) ? in[base + k] : 0u;
    #pragma unroll
    for (int k = 0; k < 8; k++) { pre[k] = s; s += v[k]; }
    uint is = wave_incl_scan(s);
    __syncthreads();
    if (lane == 63) wscr[wid] = is;
    __syncthreads();
    uint woff = 0;
    for (int wI = 0; wI < wid; wI++) woff += wscr[wI];
    uint excl = is - s + woff;
    #pragma unroll
    for (int k = 0; k < 8; k++) if (base + k < n) out[base + k] = excl + pre[k];
    __syncthreads();
}

// ---------------- phase 1: per-bucket edge & candidate histograms ----------------
__global__ __launch_bounds__(256) void bucket_hist_kernel(const int* src, const int* dst,
                                                          const int* nt, uint* bcnt, uint* bcand,
                                                          int E, int N, int NB, int shift) {
    __shared__ uint bh[NB_MAX], ch[NB_MAX];
    int tid = threadIdx.x;
    bh[tid] = 0; ch[tid] = 0;
    __syncthreads();
    int gs = gridDim.x * 256;
    for (int i = blockIdx.x * 256 + tid; i < E; i += gs) {
        int d = dst[i], s = src[i];
        if ((uint)d < (uint)N && (uint)s < (uint)N) atomicAdd(&bh[d >> shift], 1u);
    }
    for (int i = blockIdx.x * 256 + tid; i < N; i += gs) {
        if (nt[i] == 0) atomicAdd(&ch[i >> shift], 1u);
    }
    __syncthreads();
    if (bh[tid]) atomicAdd(&bcnt[tid], bh[tid]);
    if (ch[tid]) atomicAdd(&bcand[tid], ch[tid]);
}

// ---------------- phase 2: partition edges into bucket-contiguous packed staging ----------------
// staging entry: (dst_local << 17) | src   (requires N < 2^17, shift <= 15)
__global__ __launch_bounds__(256) void partition_kernel(const int* src, const int* dst,
                                                        const uint* bcnt, uint* alloc0,
                                                        uint* staging, int E, int N, int shift) {
    __shared__ uint bbase_s[NB_MAX];
    __shared__ uint lh[NB_MAX], gb[NB_MAX];
    __shared__ uint ws4[4];
    int tid = threadIdx.x;
    int lane = tid & 63, wid = tid >> 6;
    uint a = bcnt[tid];
    uint ia = wave_incl_scan(a);
    if (lane == 63) ws4[wid] = ia;
    __syncthreads();
    uint off = 0;
    for (int wI = 0; wI < wid; wI++) off += ws4[wI];
    bbase_s[tid] = ia - a + off;
    lh[tid] = 0;
    __syncthreads();
    int base = blockIdx.x * 2048;
    uint mask = (1u << shift) - 1u;
    int breg[8];
    uint rreg[8], pk8[8];
    #pragma unroll
    for (int k = 0; k < 8; k++) {
        int e = base + k * 256 + tid;
        breg[k] = -1;
        if (e < E) {
            int s = src[e], d = dst[e];
            if ((uint)d < (uint)N && (uint)s < (uint)N) {
                int b = d >> shift;
                pk8[k] = (((uint)d & mask) << 17) | (uint)s;
                breg[k] = b;
                rreg[k] = atomicAdd(&lh[b], 1u);
            }
        }
    }
    __syncthreads();
    gb[tid] = lh[tid] ? (bbase_s[tid] + atomicAdd(&alloc0[tid], lh[tid])) : 0u;
    __syncthreads();
    #pragma unroll
    for (int k = 0; k < 8; k++) {
        if (breg[k] >= 0)
            staging[gb[breg[k]] + rreg[k]] = pk8[k];
    }
}

// ---------------- phase 3: per-bucket counting sort + csr_off/dinv/cand_pos + xs rows ----------------
__global__ __launch_bounds__(256) void local_csr_kernel(const uint* staging, const uint* bcnt,
                                                        const uint* bcand, const int* nt,
                                                        const float* x,
                                                        int* csr_src, uint* csr_off, uint* cand_pos,
                                                        float* dinv, float4* xs,
                                                        int N, int shift, int NB) {
    __shared__ uint deg[NPB_MAX];
    __shared__ uint ofs[NPB_MAX];
    __shared__ uint ws4[4];
    __shared__ uint sb[4];        // ebase, eend, cb
    int b = blockIdx.x, tid = threadIdx.x;
    int lane = tid & 63, wid = tid >> 6;
    uint a = bcnt[tid];
    uint ia = wave_incl_scan(a);
    if (lane == 63) ws4[wid] = ia;
    __syncthreads();
    uint off = 0;
    for (int wI = 0; wI < wid; wI++) off += ws4[wI];
    if (tid == b) { sb[0] = ia - a + off; sb[1] = ia + off; }
    __syncthreads();
    uint c = bcand[tid];
    uint ic = wave_incl_scan(c);
    if (lane == 63) ws4[wid] = ic;
    __syncthreads();
    uint offc = 0;
    for (int wI = 0; wI < wid; wI++) offc += ws4[wI];
    if (tid == b) sb[2] = ic - c + offc;
    __syncthreads();
    uint ebase = sb[0], eend = sb[1], cb = sb[2];
    int nbase = b << shift;
    int ncount = min(1 << shift, N - nbase);
    for (int i = tid; i < ncount; i += 256) deg[i] = 0;
    __syncthreads();
    for (uint p = ebase + tid; p < eend; p += 256)
        atomicAdd(&deg[staging[p] >> 17], 1u);
    __syncthreads();
    block_excl_scan(deg, ofs, ncount, ws4);
    for (int i = tid; i < ncount; i += 256)
        csr_off[nbase + i] = ebase + ofs[i];
    if (b == NB - 1 && tid == 0) csr_off[N] = eend;
    // fused dinv + xs = x * dinv (rank-3 layer-1 trick; deg still intact)
    for (int i = tid; i < ncount; i += 256) {
        int g = nbase + i;
        float di = rsqrtf((float)(deg[i] + 1u));   // +1 self loop
        dinv[g] = di;
        xs[g] = make_float4(x[3*g] * di, x[3*g+1] * di, x[3*g+2] * di, 0.f);
    }
    __syncthreads();
    for (int i = tid; i < ncount; i += 256) deg[i] = 0;   // reuse as running counters
    __syncthreads();
    for (uint p = ebase + tid; p < eend; p += 256) {
        uint pkv = staging[p];
        uint dl = pkv >> 17;
        uint pos = ebase + ofs[dl] + atomicAdd(&deg[dl], 1u);
        csr_src[pos] = (int)(pkv & 0x1FFFFu);
    }
    __syncthreads();
    for (int i = tid; i < ncount; i += 256) deg[i] = (nt[nbase + i] == 0) ? 1u : 0u;
    __syncthreads();
    block_excl_scan(deg, ofs, ncount, ws4);
    for (int i = tid; i < ncount; i += 256) cand_pos[nbase + i] = cb + ofs[i];
}

// ---------------- layer-1 aggregate: rank-3 trick, wave-granularity node stealing ----------------
__global__ __launch_bounds__(256) void agg1_kernel(const float* xs, const int* csr_src,
                                                   const uint* csr_off, const float* dinv,
                                                   const float* W1, const float* b1, uchar* hb,
                                                   int n, float* stats_sum, float* stats_sq,
                                                   uint* gt) {
    const int tid = threadIdx.x;
    const int wave = tid >> 6;
    const int lane = tid & 63;
    const int c4 = lane & 3;
    const int slot = lane >> 2;
    const int qlead = lane & ~3;
    __shared__ float W1s[96];
    if (tid < 96) W1s[tid] = W1[tid];
    float bv[8];
    #pragma unroll
    for (int j = 0; j < 8; j++) bv[j] = b1[c4 * 8 + j];
    float bs[8], bq[8];
    #pragma unroll
    for (int j = 0; j < 8; j++) { bs[j] = 0.f; bq[j] = 0.f; }
    __syncthreads();
    while (true) {
        uint base = 0;
        if (lane == 0) base = atomicAdd(gt, 16u);
        base = (uint)__shfl((int)base, 0, 64);
        if (base >= (uint)n) break;
        uint node = base + (uint)slot;
        if (node < (uint)n) {
            uint s = csr_off[node], e = csr_off[node + 1];
            float acc = xs[(size_t)node * 4 + c4];     // self loop (xs has dinv folded)
            for (uint p = s; p < e; p += 8) {
                uint idx[8];
                float wg[8];
                #pragma unroll
                for (int j = 0; j < 8; j++) {
                    uint q = p + (uint)j;
                    uint qc = min(q, e - 1u);
                    idx[j] = (uint)csr_src[qc];
                    wg[j] = (q < e) ? 1.f : 0.f;
                }
                #pragma unroll
                for (int j = 0; j < 8; j++)
                    acc = fmaf(wg[j], xs[(size_t)idx[j] * 4 + c4], acc);
            }
            float u = dinv[node] * acc;
            float u0 = __shfl(u, qlead, 64);
            float u1 = __shfl(u, qlead + 1, 64);
            float u2 = __shfl(u, qlead + 2, 64);
            float hv[8];
            #pragma unroll
            for (int j = 0; j < 8; j++) {
                int ch = c4 * 8 + j;
                float o = u0 * W1s[ch] + u1 * W1s[32 + ch] + u2 * W1s[64 + ch] + bv[j];
                hv[j] = fmaxf(o, 0.f);
            }
            *(uint2*)(hb + (size_t)node * 32 + c4 * 8) = enc8(hv);
            #pragma unroll
            for (int j = 0; j < 8; j++) { bs[j] += hv[j]; bq[j] += hv[j] * hv[j]; }
        }
    }
    #pragma unroll
    for (int m = 4; m < 64; m <<= 1) {
        #pragma unroll
        for (int j = 0; j < 8; j++) {
            bs[j] += __shfl_xor(bs[j], m, 64);
            bq[j] += __shfl_xor(bq[j], m, 64);
        }
    }
    __shared__ float ssum[4][32], ssq[4][32];
    if (slot == 0) {
        #pragma unroll
        for (int j = 0; j < 8; j++) { ssum[wave][c4 * 8 + j] = bs[j]; ssq[wave][c4 * 8 + j] = bq[j]; }
    }
    __syncthreads();
    if (tid < 32) {
        atomicAdd(&stats_sum[tid], ssum[0][tid] + ssum[1][tid] + ssum[2][tid] + ssum[3][tid]);
        atomicAdd(&stats_sq[tid],  ssq[0][tid] + ssq[1][tid] + ssq[2][tid] + ssq[3][tid]);
    }
}

// ---------------- folded GEMM with inline BN fold (fp8 in/out) ----------------
__global__ __launch_bounds__(256) void gemmf_kernel(const uchar* hb, const float* stats_sum,
                                                    const float* stats_sq, const float* g,
                                                    const float* be, const float* W,
                                                    const float* dinv, uchar* zb, int n,
                                                    float inv_n) {
    __shared__ float Ws[1024];
    __shared__ float cs[32];
    __shared__ float a_s[32], d_s[32];
    int tid = threadIdx.x;
    if (tid < 32) {
        float mu = stats_sum[tid] * inv_n;
        float var = fmaxf(stats_sq[tid] * inv_n - mu * mu, 0.f);
        float a = g[tid] * rsqrtf(var + 1e-5f);
        a_s[tid] = a;
        d_s[tid] = be[tid] - mu * a;
    }
    __syncthreads();
    #pragma unroll
    for (int t = tid; t < 1024; t += 256) Ws[t] = a_s[t >> 5] * W[t];
    if (tid < 32) {
        float c = 0.f;
        for (int k = 0; k < 32; k++) c += d_s[k] * W[k * 32 + tid];
        cs[tid] = c;
    }
    __syncthreads();
    int i = blockIdx.x * 256 + tid;
    if (i >= n) return;
    float hk[32], acc[32];
    dec32(hb + (size_t)i * 32, hk);
    #pragma unroll
    for (int j = 0; j < 32; j++) acc[j] = cs[j];
    #pragma unroll
    for (int k = 0; k < 32; k++) {
        float h0 = hk[k];
        #pragma unroll
        for (int j = 0; j < 32; j++) acc[j] += h0 * Ws[k * 32 + j];
    }
    float di = dinv[i];
    #pragma unroll
    for (int j = 0; j < 32; j++) acc[j] *= di;
    enc32(acc, zb + (size_t)i * 32);
}

// ---------------- aggregate (layers 2/3): quad-lane, wave-granularity node stealing ----------------
template<int MODE>
__global__ __launch_bounds__(256) void agg_kernel(const uchar* zb, const int* csr_src,
                                                  const uint* csr_off, const float* dinv,
                                                  const float* bias, uchar* hb, int n,
                                                  float* stats_sum, float* stats_sq,
                                                  float* rowsum, uint* maxkey, uint* gt) {
    const int tid = threadIdx.x;
    const int wave = tid >> 6;
    const int lane = tid & 63;
    const int c4 = lane & 3;
    const int slot = lane >> 2;
    float bv[8];
    #pragma unroll
    for (int j = 0; j < 8; j++) bv[j] = bias[c4 * 8 + j];
    float bs[8], bq[8];
    if (MODE == 0) {
        #pragma unroll
        for (int j = 0; j < 8; j++) { bs[j] = 0.f; bq[j] = 0.f; }
    }
    float lmax = -3.0e38f;
    while (true) {
        uint base = 0;
        if (lane == 0) base = atomicAdd(gt, 16u);
        base = (uint)__shfl((int)base, 0, 64);
        if (base >= (uint)n) break;
        uint node = base + (uint)slot;
        if (node < (uint)n) {
            uint s = csr_off[node], e = csr_off[node + 1];
            float acc[8];
            dec8(*(const uint2*)(zb + (size_t)node * 32 + c4 * 8), acc);   // self loop
            for (uint p = s; p < e; p += 8) {
                uint idx[8];
                float wg[8];
                #pragma unroll
                for (int j = 0; j < 8; j++) {
                    uint q = p + (uint)j;
                    uint qc = min(q, e - 1u);
                    idx[j] = (uint)csr_src[qc];
                    wg[j] = (q < e) ? 1.f : 0.f;
                }
                #pragma unroll
                for (int j = 0; j < 8; j++) {
                    float t[8];
                    dec8(*(const uint2*)(zb + (size_t)idx[j] * 32 + c4 * 8), t);
                    #pragma unroll
                    for (int cI = 0; cI < 8; cI++) acc[cI] = fmaf(wg[j], t[cI], acc[cI]);
                }
            }
            float di = dinv[node];
            float hv[8];
            #pragma unroll
            for (int j = 0; j < 8; j++) hv[j] = fmaxf(di * acc[j] + bv[j], 0.f);
            *(uint2*)(hb + (size_t)node * 32 + c4 * 8) = enc8(hv);
            if (MODE == 0) {
                #pragma unroll
                for (int j = 0; j < 8; j++) { bs[j] += hv[j]; bq[j] += hv[j] * hv[j]; }
            } else {
                float rs = ((hv[0] + hv[1]) + (hv[2] + hv[3])) + ((hv[4] + hv[5]) + (hv[6] + hv[7]));
                rs += __shfl_xor(rs, 1, 64);
                rs += __shfl_xor(rs, 2, 64);
                if (c4 == 0) { rowsum[node] = rs; lmax = fmaxf(lmax, rs); }
            }
        }
    }
    if (MODE == 0) {
        #pragma unroll
        for (int m = 4; m < 64; m <<= 1) {
            #pragma unroll
            for (int j = 0; j < 8; j++) {
                bs[j] += __shfl_xor(bs[j], m, 64);
                bq[j] += __shfl_xor(bq[j], m, 64);
            }
        }
        __shared__ float ssum[4][32], ssq[4][32];
        if (slot == 0) {
            #pragma unroll
            for (int j = 0; j < 8; j++) { ssum[wave][c4 * 8 + j] = bs[j]; ssq[wave][c4 * 8 + j] = bq[j]; }
        }
        __syncthreads();
        if (tid < 32) {
            atomicAdd(&stats_sum[tid], ssum[0][tid] + ssum[1][tid] + ssum[2][tid] + ssum[3][tid]);
            atomicAdd(&stats_sq[tid],  ssq[0][tid] + ssq[1][tid] + ssq[2][tid] + ssq[3][tid]);
        }
    } else {
        #pragma unroll
        for (int m = 1; m < 64; m <<= 1) lmax = fmaxf(lmax, __shfl_xor(lmax, m, 64));
        __shared__ float lm[4];
        if (lane == 0) lm[wave] = lmax;
        __syncthreads();
        if (tid == 0) {
            float m = fmaxf(fmaxf(lm[0], lm[1]), fmaxf(lm[2], lm[3]));
            uint u = __float_as_uint(m);
            uint key = (u & 0x80000000u) ? ~u : (u | 0x80000000u);
            atomicMax(maxkey, key);
        }
    }
}

// ---------------- fused heads: candidate scores + softmax pooling + graph head ----------------
__global__ __launch_bounds__(256) void head_kernel(const uchar* hb, const int* nt,
                                                   const uint* pos, const float* Wc1,
                                                   const float* bc1, const float* Wc2,
                                                   const float* bc2, const float* rowsum,
                                                   const uint* maxkey, float* gvec, float* Zp,
                                                   uint* ticket, const float* Wd1,
                                                   const float* bd1, const float* Wd2,
                                                   const float* bd2, float* out, int n, int C) {
    __shared__ float W1s[512], b1s[16], W2s[16];
    __shared__ float ls[256];
    __shared__ float ge[32], tt[16];
    __shared__ int lastflag;
    int tid = threadIdx.x;
    for (int t = tid; t < 512; t += 256) W1s[t] = Wc1[t];
    if (tid < 16) { b1s[tid] = bc1[tid]; W2s[tid] = Wc2[tid]; }
    __syncthreads();
    // Part A: candidate scores
    int i = blockIdx.x * 256 + tid;
    if (i < n && nt[i] == 0) {
        float hv[32];
        dec32(hb + (size_t)i * 32, hv);
        float s = bc2[0];
        #pragma unroll
        for (int j = 0; j < 16; j++) {
            float u = b1s[j];
            #pragma unroll
            for (int k = 0; k < 32; k++) u += hv[k] * W1s[k * 16 + j];
            s += fmaxf(u, 0.f) * W2s[j];
        }
        s = fminf(fmaxf(s, -1000.f), 1000.f);
        uint p = pos[i];
        if (p < (uint)C) {
            out[p] = s;
            out[C + 1 + p] = (float)i;
        }
    }
    // Part B: pooling partials (lane reads one fp8 channel)
    uint key = *maxkey;
    float M = 0.f;
    if (key != 0u) M = (key & 0x80000000u) ? __uint_as_float(key ^ 0x80000000u) : __uint_as_float(~key);
    int lane = tid & 31, grp = tid >> 5;
    int stride = gridDim.x * 8;
    float accZ = 0.f, accg = 0.f;
    for (int node = blockIdx.x * 8 + grp; node < n; node += stride) {
        float ew = __expf(rowsum[node] - M);
        accg += fp82f(hb[(size_t)node * 32 + lane]) * ew;
        if (lane == 0) accZ += ew;
    }
    ls[tid] = accg;
    __syncthreads();
    if (tid < 32) {
        float a = 0.f;
        #pragma unroll
        for (int g = 0; g < 8; g++) a += ls[tid + 32 * g];
        atomicAdd(&gvec[tid], a);
    }
    __syncthreads();
    ls[tid] = (lane == 0) ? accZ : 0.f;
    __syncthreads();
    if (tid == 0) {
        float a = 0.f;
        for (int t = 0; t < 256; t += 32) a += ls[t];
        atomicAdd(Zp, a);
        __threadfence();
        uint old = atomicAdd(ticket, 1u);
        lastflag = (old == gridDim.x - 1) ? 1 : 0;
    }
    __syncthreads();
    // Part C: last block computes graph head
    if (lastflag) {
        __threadfence();
        if (tid < 32) ge[tid] = atomicAdd(&gvec[tid], 0.f);
        if (tid == 0) ls[0] = atomicAdd(Zp, 0.f);
        __syncthreads();
        float Zv = fmaxf(ls[0], 1e-30f);
        if (tid < 32) ge[tid] /= Zv;
        __syncthreads();
        if (tid < 16) {
            float s = bd1[tid];
            for (int k = 0; k < 32; k++) s += ge[k] * Wd1[k * 16 + tid];
            tt[tid] = fmaxf(s, 0.f);
        }
        __syncthreads();
        if (tid == 0) {
            float s = bd2[0];
            for (int j = 0; j < 16; j++) s += tt[j] * Wd2[j];
            out[C] = fminf(fmaxf(s, -1000.f), 1000.f);
        }
    }
}

// ---------------- host launch ----------------
extern "C" void kernel_launch(void* const* d_in, const int* in_sizes, int n_in,
                              void* d_out, int out_size, void* d_ws, size_t ws_size,
                              hipStream_t stream) {
    const float* x   = (const float*)d_in[0];
    const int*   ei  = (const int*)d_in[1];
    const int*   nt  = (const int*)d_in[2];
    const float* W1  = (const float*)d_in[3];  const float* b1  = (const float*)d_in[4];
    const float* W2  = (const float*)d_in[5];  const float* b2  = (const float*)d_in[6];
    const float* W3  = (const float*)d_in[7];  const float* b3  = (const float*)d_in[8];
    const float* g1  = (const float*)d_in[9];  const float* be1 = (const float*)d_in[10];
    const float* g2  = (const float*)d_in[11]; const float* be2 = (const float*)d_in[12];
    const float* Wc1 = (const float*)d_in[13]; const float* bc1 = (const float*)d_in[14];
    const float* Wc2 = (const float*)d_in[15]; const float* bc2 = (const float*)d_in[16];
    const float* Wd1 = (const float*)d_in[17]; const float* bd1 = (const float*)d_in[18];
    const float* Wd2 = (const float*)d_in[19]; const float* bd2 = (const float*)d_in[20];

    const int N = in_sizes[0] / 3;
    const int E = in_sizes[1] / 2;
    const int C = (out_size - 1) / 2;
    const int* e_src = ei;
    const int* e_dst = ei + E;
    float* out = (float*)d_out;

    // bucket geometry: nodes/bucket = 1<<shift, NB <= 256 (packing needs N < 2^17)
    int shift = 9;
    while (((N + (1 << shift) - 1) >> shift) > NB_MAX) shift++;
    const int NB = (N + (1 << shift) - 1) >> shift;

    // ---- workspace carve-up (~14 MB) ----
    char* w = (char*)d_ws;
    auto alloc = [&](size_t bytes) { void* p = (void*)w; w += (bytes + 255) & ~(size_t)255; return p; };
    float*    stats  = (float*)alloc(256 * 4);     // zeroed
    uint*     bcnt   = (uint*)alloc(NB_MAX * 4);   // zeroed
    uint*     bcand  = (uint*)alloc(NB_MAX * 4);   // zeroed
    uint*     alloc0 = (uint*)alloc(NB_MAX * 4);   // zeroed
    size_t zero_bytes = (size_t)((char*)w - (char*)stats);
    float*    dinv   = (float*)alloc((size_t)N * 4);
    uint*     csr_off= (uint*)alloc((size_t)(N + 1) * 4);
    uint*     cand_pos=(uint*)alloc((size_t)N * 4);
    float*    rowsum = (float*)alloc((size_t)N * 4);
    int*      csr_src= (int*)alloc((size_t)E * 4);
    uint*     staging= (uint*)alloc((size_t)E * 4);
    uchar*    zb     = (uchar*)alloc((size_t)N * 32);
    uchar*    hb     = (uchar*)alloc((size_t)N * 32);
    // xs (N*16B float4) aliases zb (dead until gemmf2 writes z2)
    float4*   xs     = (float4*)zb;

    float* sum1 = stats;       float* sq1 = stats + 32;
    float* sum2 = stats + 64;  float* sq2 = stats + 96;
    float* gvec = stats + 128; float* Zp  = stats + 160;
    uint* maxkey = (uint*)(stats + 161);
    uint* ticket = (uint*)(stats + 162);
    uint* gt1 = (uint*)(stats + 163);
    uint* gt2 = (uint*)(stats + 164);
    uint* gt3 = (uint*)(stats + 165);

    hipMemsetAsync(stats, 0, zero_bytes, stream);

    const int gN   = (N + 255) / 256;
    const int gPar = (E + 2047) / 2048;
    int gAgg = 1024;                                 // 4 blocks/CU; waves steal 16-node batches
    const float inv_n = 1.0f / (float)N;

    // ---- CSR build (XCD-local two-phase counting sort, packed staging) ----
    hipLaunchKernelGGL(bucket_hist_kernel, dim3(784), dim3(256), 0, stream, e_src, e_dst, nt, bcnt, bcand, E, N, NB, shift);
    hipLaunchKernelGGL(partition_kernel, dim3(gPar), dim3(256), 0, stream, e_src, e_dst, bcnt, alloc0, staging, E, N, shift);
    hipLaunchKernelGGL(local_csr_kernel, dim3(NB), dim3(256), 0, stream, staging, bcnt, bcand, nt,
                       x, csr_src, csr_off, cand_pos, dinv, xs, N, shift, NB);

    // ---- layer 1 (rank-3 aggregation + fused W1) ----
    hipLaunchKernelGGL(agg1_kernel, dim3(gAgg), dim3(256), 0, stream, (const float*)xs, csr_src, csr_off,
                       dinv, W1, b1, hb, N, sum1, sq1, gt1);

    // ---- layer 2 (BN1 folded inline) ----
    hipLaunchKernelGGL(gemmf_kernel, dim3(gN), dim3(256), 0, stream, hb, sum1, sq1, g1, be1, W2, dinv, zb, N, inv_n);
    hipLaunchKernelGGL((agg_kernel<0>), dim3(gAgg), dim3(256), 0, stream, zb, csr_src, csr_off,
                       dinv, b2, hb, N, sum2, sq2, rowsum, maxkey, gt2);

    // ---- layer 3 (BN2 folded inline) ----
    hipLaunchKernelGGL(gemmf_kernel, dim3(gN), dim3(256), 0, stream, hb, sum2, sq2, g2, be2, W3, dinv, zb, N, inv_n);
    hipLaunchKernelGGL((agg_kernel<1>), dim3(gAgg), dim3(256), 0, stream, zb, csr_src, csr_off,
                       dinv, b3, hb, N, sum1, sq1, rowsum, maxkey, gt3);

    // ---- fused heads ----
    hipLaunchKernelGGL(head_kernel, dim3(gN), dim3(256), 0, stream, hb, nt, cand_pos,
                       Wc1, bc1, Wc2, bc2, rowsum, maxkey, gvec, Zp, ticket,
                       Wd1, bd1, Wd2, bd2, out, N, C);
}

// Round 15
// 318.943 us; speedup vs baseline: 1.9130x; 1.9130x over previous
//
#include <hip/hip_runtime.h>

typedef unsigned int uint;
typedef unsigned char uchar;

#define NB_MAX 256      // max buckets
#define NPB_MAX 2048    // max nodes per bucket

#if defined(__has_builtin)
#if __has_builtin(__builtin_amdgcn_cvt_pk_f32_fp8) && __has_builtin(__builtin_amdgcn_cvt_pk_fp8_f32)
#define HW_FP8 1
#endif
#endif

typedef __attribute__((ext_vector_type(2))) float v2f;

// ---------------- fp8 e4m3 codecs (internal z/h storage) ----------------
static __device__ __forceinline__ uint f2fp8_sw(float v) {
    v = fminf(fmaxf(v, -448.f), 448.f);
    uint u = __float_as_uint(v);
    uint s = (u >> 24) & 0x80u;
    uint mag = u & 0x7FFFFFFFu;
    uint r = mag + 0x7FFFFu + ((mag >> 20) & 1u);     // RNE to 3 mantissa bits
    if (r < 0x3C800000u) return s;                    // below 2^-6 -> ±0
    uint e8 = (r - 0x3C000000u) >> 20;
    return s | min(e8, 0x7Eu);
}
static __device__ __forceinline__ float fp82f(uint b) {
    uint mag = b & 0x7Fu;
    uint bits = ((b & 0x80u) << 24) | ((mag << 20) + 0x3C000000u);
    return mag ? __uint_as_float(bits) : 0.f;
}
static __device__ __forceinline__ void dec8(uint2 v, float* o) {
#ifdef HW_FP8
    v2f a = __builtin_amdgcn_cvt_pk_f32_fp8((int)v.x, false);
    v2f b = __builtin_amdgcn_cvt_pk_f32_fp8((int)v.x, true);
    v2f c = __builtin_amdgcn_cvt_pk_f32_fp8((int)v.y, false);
    v2f d = __builtin_amdgcn_cvt_pk_f32_fp8((int)v.y, true);
    o[0]=a.x; o[1]=a.y; o[2]=b.x; o[3]=b.y;
    o[4]=c.x; o[5]=c.y; o[6]=d.x; o[7]=d.y;
#else
    o[0]=fp82f(v.x&0xFF); o[1]=fp82f((v.x>>8)&0xFF); o[2]=fp82f((v.x>>16)&0xFF); o[3]=fp82f(v.x>>24);
    o[4]=fp82f(v.y&0xFF); o[5]=fp82f((v.y>>8)&0xFF); o[6]=fp82f((v.y>>16)&0xFF); o[7]=fp82f(v.y>>24);
#endif
}
static __device__ __forceinline__ uint2 enc8(const float* o) {
#ifdef HW_FP8
    int rx = __builtin_amdgcn_cvt_pk_fp8_f32(o[0], o[1], 0, false);
    rx = __builtin_amdgcn_cvt_pk_fp8_f32(o[2], o[3], rx, true);
    int ry = __builtin_amdgcn_cvt_pk_fp8_f32(o[4], o[5], 0, false);
    ry = __builtin_amdgcn_cvt_pk_fp8_f32(o[6], o[7], ry, true);
    return make_uint2((uint)rx, (uint)ry);
#else
    uint2 r;
    r.x = f2fp8_sw(o[0]) | (f2fp8_sw(o[1])<<8) | (f2fp8_sw(o[2])<<16) | (f2fp8_sw(o[3])<<24);
    r.y = f2fp8_sw(o[4]) | (f2fp8_sw(o[5])<<8) | (f2fp8_sw(o[6])<<16) | (f2fp8_sw(o[7])<<24);
    return r;
#endif
}
static __device__ __forceinline__ void dec32(const uchar* row, float* o) {
    const uint4* r4 = (const uint4*)row;
    uint4 A = r4[0], B = r4[1];
    dec8(make_uint2(A.x,A.y), o); dec8(make_uint2(A.z,A.w), o+8);
    dec8(make_uint2(B.x,B.y), o+16); dec8(make_uint2(B.z,B.w), o+24);
}
static __device__ __forceinline__ void enc32(const float* o, uchar* row) {
    uint2 a = enc8(o), b = enc8(o+8), c = enc8(o+16), d = enc8(o+24);
    uint4* r4 = (uint4*)row;
    r4[0] = make_uint4(a.x,a.y,b.x,b.y);
    r4[1] = make_uint4(c.x,c.y,d.x,d.y);
}

// ---------------- wave-level inclusive scan (64 lanes) ----------------
static __device__ __forceinline__ unsigned wave_incl_scan(unsigned v) {
    int lane = threadIdx.x & 63;
    #pragma unroll
    for (int d = 1; d < 64; d <<= 1) {
        unsigned t = (unsigned)__shfl_up((int)v, d, 64);
        if (lane >= d) v += t;
    }
    return v;
}

// exclusive block scan: in[0..n) -> out[0..n), n <= 2048, 256 threads, wscr = shared[4]
static __device__ void block_excl_scan(const uint* in, uint* out, int n, uint* wscr) {
    int tid = threadIdx.x;
    int lane = tid & 63, wid = tid >> 6;
    int base = tid * 8;
    uint v[8], pre[8], s = 0;
    #pragma unroll
    for (int k = 0; k < 8; k++) v[k] = (base + k < n) ? in[base + k] : 0u;
    #pragma unroll
    for (int k = 0; k < 8; k++) { pre[k] = s; s += v[k]; }
    uint is = wave_incl_scan(s);
    __syncthreads();
    if (lane == 63) wscr[wid] = is;
    __syncthreads();
    uint woff = 0;
    for (int wI = 0; wI < wid; wI++) woff += wscr[wI];
    uint excl = is - s + woff;
    #pragma unroll
    for (int k = 0; k < 8; k++) if (base + k < n) out[base + k] = excl + pre[k];
    __syncthreads();
}

// ---------------- phase 1: per-bucket edge & candidate histograms ----------------
__global__ __launch_bounds__(256) void bucket_hist_kernel(const int* src, const int* dst,
                                                          const int* nt, uint* bcnt, uint* bcand,
                                                          int E, int N, int NB, int shift) {
    __shared__ uint bh[NB_MAX], ch[NB_MAX];
    int tid = threadIdx.x;
    bh[tid] = 0; ch[tid] = 0;
    __syncthreads();
    int gs = gridDim.x * 256;
    for (int i = blockIdx.x * 256 + tid; i < E; i += gs) {
        int d = dst[i], s = src[i];
        if ((uint)d < (uint)N && (uint)s < (uint)N) atomicAdd(&bh[d >> shift], 1u);
    }
    for (int i = blockIdx.x * 256 + tid; i < N; i += gs) {
        if (nt[i] == 0) atomicAdd(&ch[i >> shift], 1u);
    }
    __syncthreads();
    if (bh[tid]) atomicAdd(&bcnt[tid], bh[tid]);
    if (ch[tid]) atomicAdd(&bcand[tid], ch[tid]);
}

// ---------------- phase 2: partition edges into bucket-contiguous packed staging ----------------
// staging entry: (dst_local << 17) | src   (requires N < 2^17, shift <= 15)
__global__ __launch_bounds__(256) void partition_kernel(const int* src, const int* dst,
                                                        const uint* bcnt, uint* alloc0,
                                                        uint* staging, int E, int N, int shift) {
    __shared__ uint bbase_s[NB_MAX];
    __shared__ uint lh[NB_MAX], gb[NB_MAX];
    __shared__ uint ws4[4];
    int tid = threadIdx.x;
    int lane = tid & 63, wid = tid >> 6;
    uint a = bcnt[tid];
    uint ia = wave_incl_scan(a);
    if (lane == 63) ws4[wid] = ia;
    __syncthreads();
    uint off = 0;
    for (int wI = 0; wI < wid; wI++) off += ws4[wI];
    bbase_s[tid] = ia - a + off;
    lh[tid] = 0;
    __syncthreads();
    int base = blockIdx.x * 2048;
    uint mask = (1u << shift) - 1u;
    int breg[8];
    uint rreg[8], pk8[8];
    #pragma unroll
    for (int k = 0; k < 8; k++) {
        int e = base + k * 256 + tid;
        breg[k] = -1;
        if (e < E) {
            int s = src[e], d = dst[e];
            if ((uint)d < (uint)N && (uint)s < (uint)N) {
                int b = d >> shift;
                pk8[k] = (((uint)d & mask) << 17) | (uint)s;
                breg[k] = b;
                rreg[k] = atomicAdd(&lh[b], 1u);
            }
        }
    }
    __syncthreads();
    gb[tid] = lh[tid] ? (bbase_s[tid] + atomicAdd(&alloc0[tid], lh[tid])) : 0u;
    __syncthreads();
    #pragma unroll
    for (int k = 0; k < 8; k++) {
        if (breg[k] >= 0)
            staging[gb[breg[k]] + rreg[k]] = pk8[k];
    }
}

// ---------------- phase 3: per-bucket counting sort + csr_off/dinv/cand_pos + xs rows ----------------
__global__ __launch_bounds__(256) void local_csr_kernel(const uint* staging, const uint* bcnt,
                                                        const uint* bcand, const int* nt,
                                                        const float* x,
                                                        int* csr_src, uint* csr_off, uint* cand_pos,
                                                        float* dinv, float4* xs,
                                                        int N, int shift, int NB) {
    __shared__ uint deg[NPB_MAX];
    __shared__ uint ofs[NPB_MAX];
    __shared__ uint ws4[4];
    __shared__ uint sb[4];        // ebase, eend, cb
    int b = blockIdx.x, tid = threadIdx.x;
    int lane = tid & 63, wid = tid >> 6;
    uint a = bcnt[tid];
    uint ia = wave_incl_scan(a);
    if (lane == 63) ws4[wid] = ia;
    __syncthreads();
    uint off = 0;
    for (int wI = 0; wI < wid; wI++) off += ws4[wI];
    if (tid == b) { sb[0] = ia - a + off; sb[1] = ia + off; }
    __syncthreads();
    uint c = bcand[tid];
    uint ic = wave_incl_scan(c);
    if (lane == 63) ws4[wid] = ic;
    __syncthreads();
    uint offc = 0;
    for (int wI = 0; wI < wid; wI++) offc += ws4[wI];
    if (tid == b) sb[2] = ic - c + offc;
    __syncthreads();
    uint ebase = sb[0], eend = sb[1], cb = sb[2];
    int nbase = b << shift;
    int ncount = min(1 << shift, N - nbase);
    for (int i = tid; i < ncount; i += 256) deg[i] = 0;
    __syncthreads();
    for (uint p = ebase + tid; p < eend; p += 256)
        atomicAdd(&deg[staging[p] >> 17], 1u);
    __syncthreads();
    block_excl_scan(deg, ofs, ncount, ws4);
    for (int i = tid; i < ncount; i += 256)
        csr_off[nbase + i] = ebase + ofs[i];
    if (b == NB - 1 && tid == 0) csr_off[N] = eend;
    // fused dinv + xs = x * dinv (rank-3 layer-1 trick; deg still intact)
    for (int i = tid; i < ncount; i += 256) {
        int g = nbase + i;
        float di = rsqrtf((float)(deg[i] + 1u));   // +1 self loop
        dinv[g] = di;
        xs[g] = make_float4(x[3*g] * di, x[3*g+1] * di, x[3*g+2] * di, 0.f);
    }
    __syncthreads();
    for (int i = tid; i < ncount; i += 256) deg[i] = 0;   // reuse as running counters
    __syncthreads();
    for (uint p = ebase + tid; p < eend; p += 256) {
        uint pkv = staging[p];
        uint dl = pkv >> 17;
        uint pos = ebase + ofs[dl] + atomicAdd(&deg[dl], 1u);
        csr_src[pos] = (int)(pkv & 0x1FFFFu);
    }
    __syncthreads();
    for (int i = tid; i < ncount; i += 256) deg[i] = (nt[nbase + i] == 0) ? 1u : 0u;
    __syncthreads();
    block_excl_scan(deg, ofs, ncount, ws4);
    for (int i = tid; i < ncount; i += 256) cand_pos[nbase + i] = cb + ofs[i];
}

// ---------------- layer-1 aggregate: rank-3 trick, block-level work-stealing chunks ----------------
__global__ __launch_bounds__(256) void agg1_kernel(const float* xs, const int* csr_src,
                                                   const uint* csr_off, const float* dinv,
                                                   const float* W1, const float* b1, uchar* hb,
                                                   int n, float* stats_sum, float* stats_sq,
                                                   uint* gt) {
    const int tid = threadIdx.x;
    const int wave = tid >> 6;
    const int lane = tid & 63;
    const int c4 = lane & 3;
    const int slot = lane >> 2;
    const int qlead = lane & ~3;
    __shared__ float W1s[96];
    __shared__ uint s_lt, s_chunk;
    if (tid < 96) W1s[tid] = W1[tid];
    float bv[8];
    #pragma unroll
    for (int j = 0; j < 8; j++) bv[j] = b1[c4 * 8 + j];
    float bs[8], bq[8];
    #pragma unroll
    for (int j = 0; j < 8; j++) { bs[j] = 0.f; bq[j] = 0.f; }
    __syncthreads();
    while (true) {
        if (tid == 0) s_chunk = atomicAdd(gt, 1u);
        __syncthreads();
        uint cbase = s_chunk * 128u;
        if (cbase >= (uint)n) break;
        uint avail = min((uint)n - cbase, 128u);
        if (tid == 0) s_lt = 0u;
        __syncthreads();
        while (true) {
            uint li = 0;
            if (c4 == 0) li = atomicAdd(&s_lt, 1u);
            li = (uint)__shfl((int)li, qlead, 64);
            if (li >= avail) break;
            uint node = cbase + li;
            uint s = csr_off[node], e = csr_off[node + 1];
            float acc = xs[(size_t)node * 4 + c4];     // self loop (xs has dinv folded)
            for (uint p = s; p < e; p += 8) {
                uint idx[8];
                float wg[8];
                #pragma unroll
                for (int j = 0; j < 8; j++) {
                    uint q = p + (uint)j;
                    uint qc = min(q, e - 1u);
                    idx[j] = (uint)csr_src[qc];
                    wg[j] = (q < e) ? 1.f : 0.f;
                }
                #pragma unroll
                for (int j = 0; j < 8; j++)
                    acc = fmaf(wg[j], xs[(size_t)idx[j] * 4 + c4], acc);
            }
            float u = dinv[node] * acc;
            float u0 = __shfl(u, qlead, 64);
            float u1 = __shfl(u, qlead + 1, 64);
            float u2 = __shfl(u, qlead + 2, 64);
            float hv[8];
            #pragma unroll
            for (int j = 0; j < 8; j++) {
                int ch = c4 * 8 + j;
                float o = u0 * W1s[ch] + u1 * W1s[32 + ch] + u2 * W1s[64 + ch] + bv[j];
                hv[j] = fmaxf(o, 0.f);
            }
            *(uint2*)(hb + (size_t)node * 32 + c4 * 8) = enc8(hv);
            #pragma unroll
            for (int j = 0; j < 8; j++) { bs[j] += hv[j]; bq[j] += hv[j] * hv[j]; }
        }
        __syncthreads();
    }
    #pragma unroll
    for (int m = 4; m < 64; m <<= 1) {
        #pragma unroll
        for (int j = 0; j < 8; j++) {
            bs[j] += __shfl_xor(bs[j], m, 64);
            bq[j] += __shfl_xor(bq[j], m, 64);
        }
    }
    __shared__ float ssum[4][32], ssq[4][32];
    if (slot == 0) {
        #pragma unroll
        for (int j = 0; j < 8; j++) { ssum[wave][c4 * 8 + j] = bs[j]; ssq[wave][c4 * 8 + j] = bq[j]; }
    }
    __syncthreads();
    if (tid < 32) {
        atomicAdd(&stats_sum[tid], ssum[0][tid] + ssum[1][tid] + ssum[2][tid] + ssum[3][tid]);
        atomicAdd(&stats_sq[tid],  ssq[0][tid] + ssq[1][tid] + ssq[2][tid] + ssq[3][tid]);
    }
}

// ---------------- folded GEMM with inline BN fold (fp8 in/out) ----------------
__global__ __launch_bounds__(256) void gemmf_kernel(const uchar* hb, const float* stats_sum,
                                                    const float* stats_sq, const float* g,
                                                    const float* be, const float* W,
                                                    const float* dinv, uchar* zb, int n,
                                                    float inv_n) {
    __shared__ float Ws[1024];
    __shared__ float cs[32];
    __shared__ float a_s[32], d_s[32];
    int tid = threadIdx.x;
    if (tid < 32) {
        float mu = stats_sum[tid] * inv_n;
        float var = fmaxf(stats_sq[tid] * inv_n - mu * mu, 0.f);
        float a = g[tid] * rsqrtf(var + 1e-5f);
        a_s[tid] = a;
        d_s[tid] = be[tid] - mu * a;
    }
    __syncthreads();
    #pragma unroll
    for (int t = tid; t < 1024; t += 256) Ws[t] = a_s[t >> 5] * W[t];
    if (tid < 32) {
        float c = 0.f;
        for (int k = 0; k < 32; k++) c += d_s[k] * W[k * 32 + tid];
        cs[tid] = c;
    }
    __syncthreads();
    int i = blockIdx.x * 256 + tid;
    if (i >= n) return;
    float hk[32], acc[32];
    dec32(hb + (size_t)i * 32, hk);
    #pragma unroll
    for (int j = 0; j < 32; j++) acc[j] = cs[j];
    #pragma unroll
    for (int k = 0; k < 32; k++) {
        float h0 = hk[k];
        #pragma unroll
        for (int j = 0; j < 32; j++) acc[j] += h0 * Ws[k * 32 + j];
    }
    float di = dinv[i];
    #pragma unroll
    for (int j = 0; j < 32; j++) acc[j] *= di;
    enc32(acc, zb + (size_t)i * 32);
}

// ---------------- aggregate (layers 2/3): quad-lane, block-level work-stealing chunks ----------------
template<int MODE>
__global__ __launch_bounds__(256) void agg_kernel(const uchar* zb, const int* csr_src,
                                                  const uint* csr_off, const float* dinv,
                                                  const float* bias, uchar* hb, int n,
                                                  float* stats_sum, float* stats_sq,
                                                  float* rowsum, uint* maxkey, uint* gt) {
    const int tid = threadIdx.x;
    const int wave = tid >> 6;
    const int lane = tid & 63;
    const int c4 = lane & 3;
    const int slot = lane >> 2;
    const int qlead = lane & ~3;
    __shared__ uint s_lt, s_chunk;
    float bv[8];
    #pragma unroll
    for (int j = 0; j < 8; j++) bv[j] = bias[c4 * 8 + j];
    float bs[8], bq[8];
    if (MODE == 0) {
        #pragma unroll
        for (int j = 0; j < 8; j++) { bs[j] = 0.f; bq[j] = 0.f; }
    }
    float lmax = -3.0e38f;
    while (true) {
        if (tid == 0) s_chunk = atomicAdd(gt, 1u);
        __syncthreads();
        uint cbase = s_chunk * 128u;
        if (cbase >= (uint)n) break;
        uint avail = min((uint)n - cbase, 128u);
        if (tid == 0) s_lt = 0u;
        __syncthreads();
        while (true) {
            uint li = 0;
            if (c4 == 0) li = atomicAdd(&s_lt, 1u);
            li = (uint)__shfl((int)li, qlead, 64);
            if (li >= avail) break;
            uint node = cbase + li;
            uint s = csr_off[node], e = csr_off[node + 1];
            float acc[8];
            dec8(*(const uint2*)(zb + (size_t)node * 32 + c4 * 8), acc);   // self loop
            for (uint p = s; p < e; p += 8) {
                uint idx[8];
                float wg[8];
                #pragma unroll
                for (int j = 0; j < 8; j++) {
                    uint q = p + (uint)j;
                    uint qc = min(q, e - 1u);
                    idx[j] = (uint)csr_src[qc];
                    wg[j] = (q < e) ? 1.f : 0.f;
                }
                #pragma unroll
                for (int j = 0; j < 8; j++) {
                    float t[8];
                    dec8(*(const uint2*)(zb + (size_t)idx[j] * 32 + c4 * 8), t);
                    #pragma unroll
                    for (int cI = 0; cI < 8; cI++) acc[cI] = fmaf(wg[j], t[cI], acc[cI]);
                }
            }
            float di = dinv[node];
            float hv[8];
            #pragma unroll
            for (int j = 0; j < 8; j++) hv[j] = fmaxf(di * acc[j] + bv[j], 0.f);
            *(uint2*)(hb + (size_t)node * 32 + c4 * 8) = enc8(hv);
            if (MODE == 0) {
                #pragma unroll
                for (int j = 0; j < 8; j++) { bs[j] += hv[j]; bq[j] += hv[j] * hv[j]; }
            } else {
                float rs = ((hv[0] + hv[1]) + (hv[2] + hv[3])) + ((hv[4] + hv[5]) + (hv[6] + hv[7]));
                rs += __shfl_xor(rs, 1, 64);
                rs += __shfl_xor(rs, 2, 64);
                if (c4 == 0) { rowsum[node] = rs; lmax = fmaxf(lmax, rs); }
            }
        }
        __syncthreads();
    }
    if (MODE == 0) {
        #pragma unroll
        for (int m = 4; m < 64; m <<= 1) {
            #pragma unroll
            for (int j = 0; j < 8; j++) {
                bs[j] += __shfl_xor(bs[j], m, 64);
                bq[j] += __shfl_xor(bq[j], m, 64);
            }
        }
        __shared__ float ssum[4][32], ssq[4][32];
        if (slot == 0) {
            #pragma unroll
            for (int j = 0; j < 8; j++) { ssum[wave][c4 * 8 + j] = bs[j]; ssq[wave][c4 * 8 + j] = bq[j]; }
        }
        __syncthreads();
        if (tid < 32) {
            atomicAdd(&stats_sum[tid], ssum[0][tid] + ssum[1][tid] + ssum[2][tid] + ssum[3][tid]);
            atomicAdd(&stats_sq[tid],  ssq[0][tid] + ssq[1][tid] + ssq[2][tid] + ssq[3][tid]);
        }
    } else {
        #pragma unroll
        for (int m = 1; m < 64; m <<= 1) lmax = fmaxf(lmax, __shfl_xor(lmax, m, 64));
        __shared__ float lm[4];
        if (lane == 0) lm[wave] = lmax;
        __syncthreads();
        if (tid == 0) {
            float m = fmaxf(fmaxf(lm[0], lm[1]), fmaxf(lm[2], lm[3]));
            uint u = __float_as_uint(m);
            uint key = (u & 0x80000000u) ? ~u : (u | 0x80000000u);
            atomicMax(maxkey, key);
        }
    }
}

// ---------------- fused heads: candidate scores + softmax pooling + graph head ----------------
__global__ __launch_bounds__(256) void head_kernel(const uchar* hb, const int* nt,
                                                   const uint* pos, const float* Wc1,
                                                   const float* bc1, const float* Wc2,
                                                   const float* bc2, const float* rowsum,
                                                   const uint* maxkey, float* gvec, float* Zp,
                                                   uint* ticket, const float* Wd1,
                                                   const float* bd1, const float* Wd2,
                                                   const float* bd2, float* out, int n, int C) {
    __shared__ float W1s[512], b1s[16], W2s[16];
    __shared__ float ls[256];
    __shared__ float ge[32], tt[16];
    __shared__ int lastflag;
    int tid = threadIdx.x;
    for (int t = tid; t < 512; t += 256) W1s[t] = Wc1[t];
    if (tid < 16) { b1s[tid] = bc1[tid]; W2s[tid] = Wc2[tid]; }
    __syncthreads();
    // Part A: candidate scores
    int i = blockIdx.x * 256 + tid;
    if (i < n && nt[i] == 0) {
        float hv[32];
        dec32(hb + (size_t)i * 32, hv);
        float s = bc2[0];
        #pragma unroll
        for (int j = 0; j < 16; j++) {
            float u = b1s[j];
            #pragma unroll
            for (int k = 0; k < 32; k++) u += hv[k] * W1s[k * 16 + j];
            s += fmaxf(u, 0.f) * W2s[j];
        }
        s = fminf(fmaxf(s, -1000.f), 1000.f);
        uint p = pos[i];
        if (p < (uint)C) {
            out[p] = s;
            out[C + 1 + p] = (float)i;
        }
    }
    // Part B: pooling partials (lane reads one fp8 channel)
    uint key = *maxkey;
    float M = 0.f;
    if (key != 0u) M = (key & 0x80000000u) ? __uint_as_float(key ^ 0x80000000u) : __uint_as_float(~key);
    int lane = tid & 31, grp = tid >> 5;
    int stride = gridDim.x * 8;
    float accZ = 0.f, accg = 0.f;
    for (int node = blockIdx.x * 8 + grp; node < n; node += stride) {
        float ew = __expf(rowsum[node] - M);
        accg += fp82f(hb[(size_t)node * 32 + lane]) * ew;
        if (lane == 0) accZ += ew;
    }
    ls[tid] = accg;
    __syncthreads();
    if (tid < 32) {
        float a = 0.f;
        #pragma unroll
        for (int g = 0; g < 8; g++) a += ls[tid + 32 * g];
        atomicAdd(&gvec[tid], a);
    }
    __syncthreads();
    ls[tid] = (lane == 0) ? accZ : 0.f;
    __syncthreads();
    if (tid == 0) {
        float a = 0.f;
        for (int t = 0; t < 256; t += 32) a += ls[t];
        atomicAdd(Zp, a);
        __threadfence();
        uint old = atomicAdd(ticket, 1u);
        lastflag = (old == gridDim.x - 1) ? 1 : 0;
    }
    __syncthreads();
    // Part C: last block computes graph head
    if (lastflag) {
        __threadfence();
        if (tid < 32) ge[tid] = atomicAdd(&gvec[tid], 0.f);
        if (tid == 0) ls[0] = atomicAdd(Zp, 0.f);
        __syncthreads();
        float Zv = fmaxf(ls[0], 1e-30f);
        if (tid < 32) ge[tid] /= Zv;
        __syncthreads();
        if (tid < 16) {
            float s = bd1[tid];
            for (int k = 0; k < 32; k++) s += ge[k] * Wd1[k * 16 + tid];
            tt[tid] = fmaxf(s, 0.f);
        }
        __syncthreads();
        if (tid == 0) {
            float s = bd2[0];
            for (int j = 0; j < 16; j++) s += tt[j] * Wd2[j];
            out[C] = fminf(fmaxf(s, -1000.f), 1000.f);
        }
    }
}

// ---------------- host launch ----------------
extern "C" void kernel_launch(void* const* d_in, const int* in_sizes, int n_in,
                              void* d_out, int out_size, void* d_ws, size_t ws_size,
                              hipStream_t stream) {
    const float* x   = (const float*)d_in[0];
    const int*   ei  = (const int*)d_in[1];
    const int*   nt  = (const int*)d_in[2];
    const float* W1  = (const float*)d_in[3];  const float* b1  = (const float*)d_in[4];
    const float* W2  = (const float*)d_in[5];  const float* b2  = (const float*)d_in[6];
    const float* W3  = (const float*)d_in[7];  const float* b3  = (const float*)d_in[8];
    const float* g1  = (const float*)d_in[9];  const float* be1 = (const float*)d_in[10];
    const float* g2  = (const float*)d_in[11]; const float* be2 = (const float*)d_in[12];
    const float* Wc1 = (const float*)d_in[13]; const float* bc1 = (const float*)d_in[14];
    const float* Wc2 = (const float*)d_in[15]; const float* bc2 = (const float*)d_in[16];
    const float* Wd1 = (const float*)d_in[17]; const float* bd1 = (const float*)d_in[18];
    const float* Wd2 = (const float*)d_in[19]; const float* bd2 = (const float*)d_in[20];

    const int N = in_sizes[0] / 3;
    const int E = in_sizes[1] / 2;
    const int C = (out_size - 1) / 2;
    const int* e_src = ei;
    const int* e_dst = ei + E;
    float* out = (float*)d_out;

    // bucket geometry: nodes/bucket = 1<<shift, NB <= 256 (packing needs N < 2^17)
    int shift = 9;
    while (((N + (1 << shift) - 1) >> shift) > NB_MAX) shift++;
    const int NB = (N + (1 << shift) - 1) >> shift;

    // ---- workspace carve-up (~14 MB) ----
    char* w = (char*)d_ws;
    auto alloc = [&](size_t bytes) { void* p = (void*)w; w += (bytes + 255) & ~(size_t)255; return p; };
    float*    stats  = (float*)alloc(256 * 4);     // zeroed
    uint*     bcnt   = (uint*)alloc(NB_MAX * 4);   // zeroed
    uint*     bcand  = (uint*)alloc(NB_MAX * 4);   // zeroed
    uint*     alloc0 = (uint*)alloc(NB_MAX * 4);   // zeroed
    size_t zero_bytes = (size_t)((char*)w - (char*)stats);
    float*    dinv   = (float*)alloc((size_t)N * 4);
    uint*     csr_off= (uint*)alloc((size_t)(N + 1) * 4);
    uint*     cand_pos=(uint*)alloc((size_t)N * 4);
    float*    rowsum = (float*)alloc((size_t)N * 4);
    int*      csr_src= (int*)alloc((size_t)E * 4);
    uint*     staging= (uint*)alloc((size_t)E * 4);
    uchar*    zb     = (uchar*)alloc((size_t)N * 32);
    uchar*    hb     = (uchar*)alloc((size_t)N * 32);
    // xs (N*16B float4) aliases zb (dead until gemmf2 writes z2)
    float4*   xs     = (float4*)zb;

    float* sum1 = stats;       float* sq1 = stats + 32;
    float* sum2 = stats + 64;  float* sq2 = stats + 96;
    float* gvec = stats + 128; float* Zp  = stats + 160;
    uint* maxkey = (uint*)(stats + 161);
    uint* ticket = (uint*)(stats + 162);
    uint* gt1 = (uint*)(stats + 163);
    uint* gt2 = (uint*)(stats + 164);
    uint* gt3 = (uint*)(stats + 165);

    hipMemsetAsync(stats, 0, zero_bytes, stream);

    const int gN   = (N + 255) / 256;
    const int gPar = (E + 2047) / 2048;
    int gAgg = (N + 127) / 128;
    if (gAgg > 512) gAgg = 512;                     // block-level work stealing, ~780 atomics total
    const float inv_n = 1.0f / (float)N;

    // ---- CSR build (XCD-local two-phase counting sort, packed staging) ----
    hipLaunchKernelGGL(bucket_hist_kernel, dim3(784), dim3(256), 0, stream, e_src, e_dst, nt, bcnt, bcand, E, N, NB, shift);
    hipLaunchKernelGGL(partition_kernel, dim3(gPar), dim3(256), 0, stream, e_src, e_dst, bcnt, alloc0, staging, E, N, shift);
    hipLaunchKernelGGL(local_csr_kernel, dim3(NB), dim3(256), 0, stream, staging, bcnt, bcand, nt,
                       x, csr_src, csr_off, cand_pos, dinv, xs, N, shift, NB);

    // ---- layer 1 (rank-3 aggregation + fused W1) ----
    hipLaunchKernelGGL(agg1_kernel, dim3(gAgg), dim3(256), 0, stream, (const float*)xs, csr_src, csr_off,
                       dinv, W1, b1, hb, N, sum1, sq1, gt1);

    // ---- layer 2 (BN1 folded inline) ----
    hipLaunchKernelGGL(gemmf_kernel, dim3(gN), dim3(256), 0, stream, hb, sum1, sq1, g1, be1, W2, dinv, zb, N, inv_n);
    hipLaunchKernelGGL((agg_kernel<0>), dim3(gAgg), dim3(256), 0, stream, zb, csr_src, csr_off,
                       dinv, b2, hb, N, sum2, sq2, rowsum, maxkey, gt2);

    // ---- layer 3 (BN2 folded inline) ----
    hipLaunchKernelGGL(gemmf_kernel, dim3(gN), dim3(256), 0, stream, hb, sum2, sq2, g2, be2, W3, dinv, zb, N, inv_n);
    hipLaunchKernelGGL((agg_kernel<1>), dim3(gAgg), dim3(256), 0, stream, zb, csr_src, csr_off,
                       dinv, b3, hb, N, sum1, sq1, rowsum, maxkey, gt3);

    // ---- fused heads ----
    hipLaunchKernelGGL(head_kernel, dim3(gN), dim3(256), 0, stream, hb, nt, cand_pos,
                       Wc1, bc1, Wc2, bc2, rowsum, maxkey, gvec, Zp, ticket,
                       Wd1, bd1, Wd2, bd2, out, N, C);
}